// Round 4
// baseline (231.375 us; speedup 1.0000x reference)
//
#include <hip/hip_runtime.h>
#include <cstddef>

#define NCAPS  10
#define BATCH  256
#define NROUTE 1152
#define CIN    8
#define COUT   16
#define T      768          // threads per block (12 waves = exactly 3 waves/EU)
#define RPT    3            // (route, half) units per thread: 1152*2/768
#define NB     4            // batch elements per block
#define NWAVE  (T / 64)
#define NBLK   (NCAPS * (BATCH / NB))   // 640 blocks

// full-wave scalar sum (pair-duplicated inputs give exactly 2x the true sum)
__device__ __forceinline__ float wave_sum(float v) {
    v += __shfl_xor(v, 1);  v += __shfl_xor(v, 2);  v += __shfl_xor(v, 4);
    v += __shfl_xor(v, 8);  v += __shfl_xor(v, 16); v += __shfl_xor(v, 32);
    return v;
}

// Component-splitting butterfly over 8 components held per-lane, reducing
// across the 64 lanes with masks {2,4,8} then scalar {16,32}. On return,
// lane L (L<16) holds in s[0] the wave-total of component
//   comp(L) = (L&1)*8 + 4*((L>>1)&1) + 2*((L>>2)&1) + ((L>>3)&1)
__device__ __forceinline__ float wave_sum8(float* s, int lane) {
#pragma unroll
    for (int j = 0; j < 4; ++j) {
        float snd = (lane & 2) ? s[j] : s[j + 4];
        float r = __shfl_xor(snd, 2);
        s[j] = ((lane & 2) ? s[j + 4] : s[j]) + r;
    }
#pragma unroll
    for (int j = 0; j < 2; ++j) {
        float snd = (lane & 4) ? s[j] : s[j + 2];
        float r = __shfl_xor(snd, 4);
        s[j] = ((lane & 4) ? s[j + 2] : s[j]) + r;
    }
    {
        float snd = (lane & 8) ? s[0] : s[1];
        float r = __shfl_xor(snd, 8);
        s[0] = ((lane & 8) ? s[1] : s[0]) + r;
    }
    s[0] += __shfl_xor(s[0], 16);
    s[0] += __shfl_xor(s[0], 32);
    return s[0];
}

// waves_per_eu(3,3): pin occupancy to exactly 3 waves/EU (1 block/CU).
// Rounds 1-3 lesson: with 12-wave blocks the allocator's occupancy heuristic
// picked 2 blocks/CU (85-VGPR budget) and spilled ~50 floats/thread ->
// 350-580 MB of scratch HBM traffic. max=3 forbids that choice; budget = 170.
__global__ __launch_bounds__(T) __attribute__((amdgpu_waves_per_eu(3, 3)))
void caps_routing(const float* __restrict__ x,
                  const float* __restrict__ W,
                  float* __restrict__ out) {
    __shared__ float sred[NWAVE][NB][20];   // [wave][b][comp 0..15, 16=sumExp]
    __shared__ float outLDS[NB][COUT];

    const int tid  = threadIdx.x;
    const int lane = tid & 63;
    const int wv   = tid >> 6;
    const int h    = tid & 1;        // output half
    const int rb   = tid >> 1;       // route base 0..383

    // XCD-aware swizzle: each XCD sees a contiguous widx range -> touches <=2
    // capsules -> W working set <=1.18MB, stays in its 4MB L2.
    int g    = blockIdx.x;
    int widx = (g & 7) * (NBLK / 8) + (g >> 3);   // bijective, 640 % 8 == 0
    int c    = widx >> 6;                          // / (BATCH/NB = 64)
    int b0   = (widx & 63) * NB;

    const float* Wc = W + (size_t)c * (NROUTE * CIN * COUT);
    const float* xb = x + (size_t)b0 * (NROUTE * CIN);

    // priors in registers: pr[b][k][j], thread owns route rb+k*384, half h
    float pr[NB][RPT][8];

    // ---------------- Phase A: priors = x . W (half-row per thread) --------
#pragma unroll
    for (int k = 0; k < RPT; ++k) {
        const int r = rb + k * (T / 2);
        const float4* wp = reinterpret_cast<const float4*>(Wc + (size_t)r * (CIN * COUT) + h * 8);
        float xs[NB][CIN];
#pragma unroll
        for (int b = 0; b < NB; ++b) {
            const float4* xq = reinterpret_cast<const float4*>(xb + (size_t)b * (NROUTE * CIN) + r * CIN);
            float4 xa = xq[0], xv = xq[1];
            xs[b][0] = xa.x; xs[b][1] = xa.y; xs[b][2] = xa.z; xs[b][3] = xa.w;
            xs[b][4] = xv.x; xs[b][5] = xv.y; xs[b][6] = xv.z; xs[b][7] = xv.w;
#pragma unroll
            for (int j = 0; j < 8; ++j) pr[b][k][j] = 0.f;
        }
#pragma unroll
        for (int i = 0; i < CIN; ++i) {
            float4 wA = wp[i * 4];       // W[r][i][h*8 .. h*8+3]
            float4 wB = wp[i * 4 + 1];   // W[r][i][h*8+4 .. h*8+7]
#pragma unroll
            for (int b = 0; b < NB; ++b) {
                const float xi = xs[b][i];
                pr[b][k][0] = fmaf(xi, wA.x, pr[b][k][0]);
                pr[b][k][1] = fmaf(xi, wA.y, pr[b][k][1]);
                pr[b][k][2] = fmaf(xi, wA.z, pr[b][k][2]);
                pr[b][k][3] = fmaf(xi, wA.w, pr[b][k][3]);
                pr[b][k][4] = fmaf(xi, wB.x, pr[b][k][4]);
                pr[b][k][5] = fmaf(xi, wB.y, pr[b][k][5]);
                pr[b][k][6] = fmaf(xi, wB.z, pr[b][k][6]);
                pr[b][k][7] = fmaf(xi, wB.w, pr[b][k][7]);
            }
        }
    }

    // ---------------- Phase B: 3 routing iterations ----------------
    float l[NB][RPT];
#pragma unroll
    for (int b = 0; b < NB; ++b)
#pragma unroll
        for (int k = 0; k < RPT; ++k) l[b][k] = 0.f;

    for (int it = 0; it < 3; ++it) {
#pragma unroll
        for (int b = 0; b < NB; ++b) {
            float og8[8];
            if (it > 0) {
#pragma unroll
                for (int j = 0; j < 8; ++j) og8[j] = outLDS[b][h * 8 + j];
            }
            float s8[8];
            float se = 0.f;
#pragma unroll
            for (int j = 0; j < 8; ++j) s8[j] = 0.f;

#pragma unroll
            for (int k = 0; k < RPT; ++k) {
                if (it > 0) {
                    float d = 0.f;
#pragma unroll
                    for (int j = 0; j < 8; ++j) d = fmaf(pr[b][k][j], og8[j], d);
                    d += __shfl_xor(d, 1);   // combine halves -> full 16-dot
                    l[b][k] += d;
                }
                const float e = __expf(l[b][k]);   // logits bounded ~|45|
                se += e;
#pragma unroll
                for (int j = 0; j < 8; ++j) s8[j] = fmaf(e, pr[b][k][j], s8[j]);
            }

            const float sv  = wave_sum8(s8, lane);
            const float sev = wave_sum(se);   // pair-duplicated: exactly 2x true sum
            if (lane < 16) {
                const int o = (lane & 1) * 8 + 4 * ((lane >> 1) & 1)
                            + 2 * ((lane >> 2) & 1) + ((lane >> 3) & 1);
                sred[wv][b][o] = sv;
            }
            if (lane == 0) sred[wv][b][16] = sev * 0.5f;
        }
        __syncthreads();

        if (tid < NB * COUT) {           // 64 threads: one wave finishes
            const int b = tid >> 4, o = tid & 15;
            float S = 0.f, SE = 0.f;
#pragma unroll
            for (int w2 = 0; w2 < NWAVE; ++w2) {
                S  += sred[w2][b][o];
                SE += sred[w2][b][16];
            }
            const float tt = S / SE;
            float p = tt * tt;
            p += __shfl_xor(p, 1); p += __shfl_xor(p, 2);
            p += __shfl_xor(p, 4); p += __shfl_xor(p, 8);   // |s|^2 in 16-lane group
            const float scale = p / ((1.f + p) * sqrtf(p));
            const float val = tt * scale;
            outLDS[b][o] = val;
            if (it == 2) out[((size_t)c * BATCH + b0 + b) * COUT + o] = val;
        }
        __syncthreads();
    }
}

extern "C" void kernel_launch(void* const* d_in, const int* in_sizes, int n_in,
                              void* d_out, int out_size, void* d_ws, size_t ws_size,
                              hipStream_t stream) {
    const float* x = (const float*)d_in[0];
    const float* w = (const float*)d_in[1];
    float* out = (float*)d_out;
    hipLaunchKernelGGL(caps_routing, dim3(NBLK), dim3(T), 0, stream, x, w, out);
}